// Round 5
// baseline (293.123 us; speedup 1.0000x reference)
//
#include <hip/hip_runtime.h>

#define N_NODES 32768
#define C_IN 128
#define C_W 32
#define KK 24
#define SS 5
#define GG 8      // nodes per k_node block
#define AGS (KK * C_W + 4)   // padded sAgg stride (772: breaks 8-way bank conflict)

#define LD6(W, PTR) do { const float4* _p = (const float4*)(PTR); \
  W[0]=_p[0]; W[1]=_p[1]; W[2]=_p[2]; W[3]=_p[3]; W[4]=_p[4]; W[5]=_p[5]; } while(0)

#define ACC24(W, V) do { float _v = (V); \
  a[0]+=W[0].x*_v;  a[1]+=W[0].y*_v;  a[2]+=W[0].z*_v;  a[3]+=W[0].w*_v;  \
  a[4]+=W[1].x*_v;  a[5]+=W[1].y*_v;  a[6]+=W[1].z*_v;  a[7]+=W[1].w*_v;  \
  a[8]+=W[2].x*_v;  a[9]+=W[2].y*_v;  a[10]+=W[2].z*_v; a[11]+=W[2].w*_v; \
  a[12]+=W[3].x*_v; a[13]+=W[3].y*_v; a[14]+=W[3].z*_v; a[15]+=W[3].w*_v; \
  a[16]+=W[4].x*_v; a[17]+=W[4].y*_v; a[18]+=W[4].z*_v; a[19]+=W[4].w*_v; \
  a[20]+=W[5].x*_v; a[21]+=W[5].y*_v; a[22]+=W[5].z*_v; a[23]+=W[5].w*_v; } while(0)

// ---------------- colstats(x) for BN1 + edge histogram ----------------
__global__ void __launch_bounds__(256) k_pre(
        const float* __restrict__ x, float* __restrict__ s1,
        const int* __restrict__ ei, int E, int* __restrict__ counts) {
    int t = threadIdx.x;
    int c = t % C_IN;
    int r0 = blockIdx.x * 2 + t / C_IN;
    float s = 0.f, sq = 0.f;
    for (int r = r0; r < N_NODES; r += 1024) {
        float v = x[(size_t)r * C_IN + c];
        s += v; sq += v * v;
    }
    atomicAdd(&s1[c], s);
    atomicAdd(&s1[C_IN + c], sq);
    for (int e = blockIdx.x * 256 + t; e < E; e += 512 * 256)
        atomicAdd(&counts[ei[E + e]], 1);
}

// ---------------- input MLP: lrelu(bn1(x)) @ lin1_w (+ BN2 stats) ----------------
__global__ void __launch_bounds__(256) k_mlp1(
        const float* __restrict__ x, const float* __restrict__ s1,
        const float* __restrict__ g1, const float* __restrict__ b1,
        const float* __restrict__ w1, float* __restrict__ hpre,
        float* __restrict__ s2sh) {
    __shared__ float sAB[2][C_IN];
    __shared__ float sx[32][C_IN + 4];
    __shared__ float sw[C_IN][C_W];
    const int t = threadIdx.x;
    const int row0 = blockIdx.x * 32;
    if (t < C_IN) {
        float mean = s1[t] * (1.f / N_NODES);
        float var = s1[C_IN + t] * (1.f / N_NODES) - mean * mean;
        float a = g1[t] * rsqrtf(var + 1e-5f);
        sAB[0][t] = a; sAB[1][t] = b1[t] - mean * a;
    }
    for (int idx = t; idx < C_IN * C_W; idx += 256)
        sw[idx / C_W][idx % C_W] = w1[idx];
    __syncthreads();
    for (int idx = t; idx < 32 * 32; idx += 256) {
        int r = idx >> 5, cq = idx & 31;
        float4 v = *(const float4*)&x[(size_t)(row0 + r) * C_IN + cq * 4];
        float* d = &sx[r][cq * 4];
        float a0 = sAB[0][cq*4+0]*v.x + sAB[1][cq*4+0];
        float a1 = sAB[0][cq*4+1]*v.y + sAB[1][cq*4+1];
        float a2 = sAB[0][cq*4+2]*v.z + sAB[1][cq*4+2];
        float a3 = sAB[0][cq*4+3]*v.w + sAB[1][cq*4+3];
        d[0] = a0 >= 0.f ? a0 : 0.1f * a0;
        d[1] = a1 >= 0.f ? a1 : 0.1f * a1;
        d[2] = a2 >= 0.f ? a2 : 0.1f * a2;
        d[3] = a3 >= 0.f ? a3 : 0.1f * a3;
    }
    __syncthreads();
    const int r = t >> 3, c0 = (t & 7) * 4;
    float ac0 = 0.f, ac1 = 0.f, ac2 = 0.f, ac3 = 0.f;
    #pragma unroll 8
    for (int cc = 0; cc < C_IN; ++cc) {
        float xv = sx[r][cc];
        float4 wv = *(const float4*)&sw[cc][c0];
        ac0 += xv * wv.x; ac1 += xv * wv.y; ac2 += xv * wv.z; ac3 += xv * wv.w;
    }
    float4 o; o.x = ac0; o.y = ac1; o.z = ac2; o.w = ac3;
    *(float4*)&hpre[(size_t)(row0 + r) * C_W + c0] = o;
    __syncthreads();
    sx[r][c0] = ac0; sx[r][c0+1] = ac1; sx[r][c0+2] = ac2; sx[r][c0+3] = ac3;
    __syncthreads();
    if (t < C_W) {
        float s = 0.f, sq = 0.f;
        #pragma unroll
        for (int rr = 0; rr < 32; ++rr) {
            float v = sx[rr][t];
            s += v; sq += v * v;
        }
        int sh = (blockIdx.x & 7) * 64;
        atomicAdd(&s2sh[sh + t], s);
        atomicAdd(&s2sh[sh + C_W + t], sq);
    }
}

// ---------------- single-block scan (1024 thr x 32 elems, int4) ----------------
__global__ void __launch_bounds__(1024) k_scan(
        const int* __restrict__ counts, int* __restrict__ offsets,
        int* __restrict__ cursor) {
    __shared__ int sblk[1024];
    const int t = threadIdx.x;
    const int base = t * 32;
    const int4* cp = (const int4*)(counts + base);
    int loc[32];
    int s = 0;
    #pragma unroll
    for (int q = 0; q < 8; ++q) {
        int4 v = cp[q];
        loc[q*4+0] = s; s += v.x;
        loc[q*4+1] = s; s += v.y;
        loc[q*4+2] = s; s += v.z;
        loc[q*4+3] = s; s += v.w;
    }
    sblk[t] = s;
    __syncthreads();
    for (int d = 1; d < 1024; d <<= 1) {
        int u = (t >= d) ? sblk[t - d] : 0;
        __syncthreads();
        sblk[t] += u;
        __syncthreads();
    }
    const int blockbase = sblk[t] - s;
    #pragma unroll
    for (int q = 0; q < 8; ++q) {
        int4 o;
        o.x = blockbase + loc[q*4+0];
        o.y = blockbase + loc[q*4+1];
        o.z = blockbase + loc[q*4+2];
        o.w = blockbase + loc[q*4+3];
        ((int4*)(offsets + base))[q] = o;
        ((int4*)(cursor + base))[q] = o;
    }
    if (t == 1023) offsets[N_NODES] = sblk[1023];
}

// ---------------- edge kernel: WeightNet + scatter to CSR slots ----------------
__global__ void __launch_bounds__(256) k_edge(
        const int* __restrict__ ei, int E,
        const float* __restrict__ pos, const float* __restrict__ ori,
        const int* __restrict__ seq,
        const float* __restrict__ wnw, const float* __restrict__ wnb,
        int* __restrict__ cursor, int* __restrict__ srcPerm,
        float* __restrict__ wPerm) {
    __shared__ float sWnw[11][169];
    __shared__ float sWnb[11][24];
    const int t = threadIdx.x;
    for (int idx = t; idx < 11 * 168; idx += 256)
        sWnw[idx / 168][idx % 168] = wnw[idx];
    for (int idx = t; idx < 11 * 24; idx += 256)
        sWnb[idx / 24][idx % 24] = wnb[idx];
    __syncthreads();
    const int e = blockIdx.x * 256 + t;
    if (e >= E) return;
    const int src = ei[e];
    const int dst = ei[E + e];
    int ds = seq[src] - seq[dst];
    ds = ds < -SS ? -SS : (ds > SS ? SS : ds);
    const int sb = ds + SS;
    float dx = pos[src * 3 + 0] - pos[dst * 3 + 0];
    float dy = pos[src * 3 + 1] - pos[dst * 3 + 1];
    float dz = pos[src * 3 + 2] - pos[dst * 3 + 2];
    float dist = sqrtf(dx * dx + dy * dy + dz * dz);
    float inv = 1.f / (dist + 1e-9f);
    float ux = dx * inv, uy = dy * inv, uz = dz * inv;
    float b0 = ori[src * 9 + 0], b1 = ori[src * 9 + 1], b2 = ori[src * 9 + 2];
    float delta[7];
    #pragma unroll
    for (int r = 0; r < 3; ++r) {
        float m0 = ori[dst * 9 + r * 3 + 0];
        float m1 = ori[dst * 9 + r * 3 + 1];
        float m2 = ori[dst * 9 + r * 3 + 2];
        delta[r]     = m0 * ux + m1 * uy + m2 * uz;
        delta[3 + r] = m0 * b0 + m1 * b1 + m2 * b2;
    }
    delta[6] = dist * 0.125f;
    float w[KK];
    #pragma unroll
    for (int k = 0; k < KK; ++k) {
        float acc = sWnb[sb][k];
        #pragma unroll
        for (int f = 0; f < 7; ++f)
            acc += delta[f] * sWnw[sb][f * 24 + k];
        w[k] = acc >= 0.f ? acc : 0.2f * acc;
    }
    const int p = atomicAdd(&cursor[dst], 1);
    srcPerm[p] = src;
    float4* wp = (float4*)(wPerm + (size_t)p * KK);
    #pragma unroll
    for (int q = 0; q < 6; ++q) {
        float4 o; o.x = w[q*4]; o.y = w[q*4+1]; o.z = w[q*4+2]; o.w = w[q*4+3];
        wp[q] = o;
    }
}

// ---------------- aggregation + conv projection (+ BN3 stats) ----------------
__global__ void __launch_bounds__(256, 4) k_node(
    const int* __restrict__ offsets, const int* __restrict__ srcPerm,
    const float* __restrict__ wPerm, const float* __restrict__ hpre,
    const float* __restrict__ s2sh, const float* __restrict__ g2,
    const float* __restrict__ b2, const float* __restrict__ convw,
    float* __restrict__ convout, float* __restrict__ s3sh) {
    __shared__ float sA2[C_W], sB2[C_W];
    __shared__ int sOff[GG + 1];
    __shared__ float sAgg[GG][AGS];
    __shared__ float sRed[4][GG][C_W];
    __shared__ float sRv[GG][C_W], sRq[GG][C_W];
    const int i0 = blockIdx.x * GG;
    const int t = threadIdx.x;
    if (t < C_W) {
        float s = 0.f, sq = 0.f;
        #pragma unroll
        for (int j = 0; j < 8; ++j) {
            s  += s2sh[j * 64 + t];
            sq += s2sh[j * 64 + C_W + t];
        }
        float mean = s * (1.f / N_NODES);
        float var = sq * (1.f / N_NODES) - mean * mean;
        float a = g2[t] * rsqrtf(var + 1e-5f);
        sA2[t] = a; sB2[t] = b2[t] - mean * a;
    }
    if (t <= GG) sOff[t] = offsets[i0 + t];
    __syncthreads();
    const int g = t >> 5, c = t & 31;
    const float bnA = sA2[c], bnB = sB2[c];
    const int beg = sOff[g], end = sOff[g + 1];
    float a[KK];
    #pragma unroll
    for (int k = 0; k < KK; ++k) a[k] = 0.f;

    for (int cb = beg; cb < end; cb += 32) {
        const int m = min(32, end - cb);
        int srcL = (cb + c < end) ? srcPerm[cb + c] : 0;
        int j = 0;
        for (; j + 2 <= m; j += 2) {
            int s0 = __shfl(srcL, j + 0, 32);
            int s1 = __shfl(srcL, j + 1, 32);
            float h0 = hpre[(size_t)s0 * C_W + c];
            float h1 = hpre[(size_t)s1 * C_W + c];
            float4 wa[6], wb[6];
            const float* wbase = wPerm + (size_t)(cb + j) * KK;
            LD6(wa, wbase);
            LD6(wb, wbase + KK);
            float v0 = bnA * h0 + bnB; v0 = v0 >= 0.f ? v0 : 0.1f * v0;
            float v1 = bnA * h1 + bnB; v1 = v1 >= 0.f ? v1 : 0.1f * v1;
            ACC24(wa, v0);
            ACC24(wb, v1);
        }
        if (j < m) {
            int s0 = __shfl(srcL, j, 32);
            float h0 = hpre[(size_t)s0 * C_W + c];
            float4 wa[6];
            LD6(wa, wPerm + (size_t)(cb + j) * KK);
            float v0 = bnA * h0 + bnB; v0 = v0 >= 0.f ? v0 : 0.1f * v0;
            ACC24(wa, v0);
        }
    }
    #pragma unroll
    for (int k = 0; k < KK; ++k) sAgg[g][k * C_W + c] = a[k];
    __syncthreads();

    // projection: thread (coq = t&7, gp = (t>>3)&7, sl = t>>6); 192 rows/slice
    {
        const int coq = t & 7;
        const int gp  = (t >> 3) & 7;
        const int sl  = t >> 6;
        const int r0  = sl * 192;
        float4 acc; acc.x = acc.y = acc.z = acc.w = 0.f;
        #pragma unroll 4
        for (int rc = 0; rc < 192; rc += 4) {
            const float4 s4 = *(const float4*)&sAgg[gp][r0 + rc];
            const float4 w0 = *(const float4*)&convw[(size_t)(r0+rc+0)*32 + coq*4];
            const float4 w1 = *(const float4*)&convw[(size_t)(r0+rc+1)*32 + coq*4];
            const float4 w2 = *(const float4*)&convw[(size_t)(r0+rc+2)*32 + coq*4];
            const float4 w3 = *(const float4*)&convw[(size_t)(r0+rc+3)*32 + coq*4];
            acc.x += s4.x*w0.x + s4.y*w1.x + s4.z*w2.x + s4.w*w3.x;
            acc.y += s4.x*w0.y + s4.y*w1.y + s4.z*w2.y + s4.w*w3.y;
            acc.z += s4.x*w0.z + s4.y*w1.z + s4.z*w2.z + s4.w*w3.z;
            acc.w += s4.x*w0.w + s4.y*w1.w + s4.z*w2.w + s4.w*w3.w;
        }
        *(float4*)&sRed[sl][gp][coq * 4] = acc;
    }
    __syncthreads();
    {
        const int gg = t >> 5, co = t & 31;
        float v = sRed[0][gg][co] + sRed[1][gg][co] + sRed[2][gg][co] + sRed[3][gg][co];
        convout[(size_t)(i0 + gg) * C_W + co] = v;
        sRv[gg][co] = v; sRq[gg][co] = v * v;
    }
    __syncthreads();
    if (t < 64) {
        int cc = t & 31;
        bool isq = t >= C_W;
        float s = 0.f;
        #pragma unroll
        for (int gg = 0; gg < GG; ++gg)
            s += isq ? sRq[gg][cc] : sRv[gg][cc];
        atomicAdd(&s3sh[(blockIdx.x & 7) * 64 + t], s);
    }
}

// ---------------- output: lrelu(bn3(conv)) @ lin2_w + x (float4) ----------------
__global__ void __launch_bounds__(256) k_out(
        const float* __restrict__ conv, const float* __restrict__ s3sh,
        const float* __restrict__ g3, const float* __restrict__ b3,
        const float* __restrict__ w2, const float* __restrict__ x,
        float* __restrict__ out) {
    __shared__ float sAB[2][C_W];
    __shared__ float sh[8][C_W];
    __shared__ float sw2[C_W][C_IN];
    const int t = threadIdx.x;
    const int row0 = blockIdx.x * 8;
    if (t < C_W) {
        float s = 0.f, sq = 0.f;
        #pragma unroll
        for (int j = 0; j < 8; ++j) {
            s  += s3sh[j * 64 + t];
            sq += s3sh[j * 64 + C_W + t];
        }
        float mean = s * (1.f / N_NODES);
        float var = sq * (1.f / N_NODES) - mean * mean;
        float a = g3[t] * rsqrtf(var + 1e-5f);
        sAB[0][t] = a; sAB[1][t] = b3[t] - mean * a;
    }
    for (int idx = t; idx < C_W * C_IN; idx += 256)
        sw2[idx >> 7][idx & 127] = w2[idx];
    __syncthreads();
    {
        float v = conv[(size_t)row0 * C_W + t];
        int r = t >> 5, cc = t & 31;
        v = sAB[0][cc] * v + sAB[1][cc];
        sh[r][cc] = v >= 0.f ? v : 0.1f * v;
    }
    __syncthreads();
    const int r = t >> 5, c4 = (t & 31) * 4;
    float4 acc = *(const float4*)&x[(size_t)(row0 + r) * C_IN + c4];
    #pragma unroll 8
    for (int cw = 0; cw < C_W; ++cw) {
        float hv = sh[r][cw];
        float4 wv = *(const float4*)&sw2[cw][c4];
        acc.x += hv * wv.x; acc.y += hv * wv.y;
        acc.z += hv * wv.z; acc.w += hv * wv.w;
    }
    *(float4*)&out[(size_t)(row0 + r) * C_IN + c4] = acc;
}

extern "C" void kernel_launch(void* const* d_in, const int* in_sizes, int n_in,
                              void* d_out, int out_size, void* d_ws, size_t ws_size,
                              hipStream_t stream) {
    const float* x     = (const float*)d_in[0];
    const float* pos   = (const float*)d_in[1];
    const float* ori   = (const float*)d_in[2];
    const int*   seq   = (const int*)d_in[3];
    const int*   ei    = (const int*)d_in[4];
    const float* bn1g  = (const float*)d_in[5];
    const float* bn1b  = (const float*)d_in[6];
    const float* lin1w = (const float*)d_in[7];
    const float* bn2g  = (const float*)d_in[8];
    const float* bn2b  = (const float*)d_in[9];
    const float* wnw   = (const float*)d_in[10];
    const float* wnb   = (const float*)d_in[11];
    const float* convw = (const float*)d_in[12];
    const float* bn3g  = (const float*)d_in[13];
    const float* bn3b  = (const float*)d_in[14];
    const float* lin2w = (const float*)d_in[15];
    float* out = (float*)d_out;
    const int E = in_sizes[4] / 2;

    char* wsb = (char*)d_ws;
    size_t off = 0;
    auto alloc = [&](size_t bytes) {
        void* p = wsb + off;
        off = (off + bytes + 255) & ~(size_t)255;
        return p;
    };
    float* s1      = (float*)alloc(256 * 4);
    float* s2sh    = (float*)alloc(512 * 4);
    float* s3sh    = (float*)alloc(512 * 4);
    int*   counts  = (int*)alloc((size_t)N_NODES * 4);
    size_t zero_bytes = off;
    int*   offsets = (int*)alloc(((size_t)N_NODES + 1) * 4);
    int*   cursor  = (int*)alloc((size_t)N_NODES * 4);
    int*   srcPerm = (int*)alloc((size_t)E * 4);
    float* hpre    = (float*)alloc((size_t)N_NODES * C_W * 4);
    float* convo   = (float*)alloc((size_t)N_NODES * C_W * 4);
    float* wPerm   = (float*)alloc((size_t)E * KK * 4);

    hipMemsetAsync(wsb, 0, zero_bytes, stream);

    k_pre<<<512, 256, 0, stream>>>(x, s1, ei, E, counts);
    k_scan<<<1, 1024, 0, stream>>>(counts, offsets, cursor);
    k_edge<<<(E + 255) / 256, 256, 0, stream>>>(ei, E, pos, ori, seq, wnw, wnb,
                                                cursor, srcPerm, wPerm);
    k_mlp1<<<N_NODES / 32, 256, 0, stream>>>(x, s1, bn1g, bn1b, lin1w, hpre, s2sh);
    k_node<<<N_NODES / GG, 256, 0, stream>>>(offsets, srcPerm, wPerm, hpre,
                                             s2sh, bn2g, bn2b, convw, convo, s3sh);
    k_out<<<N_NODES / 8, 256, 0, stream>>>(convo, s3sh, bn3g, bn3b, lin2w, x, out);
}

// Round 7
// 275.219 us; speedup vs baseline: 1.0651x; 1.0651x over previous
//
#include <hip/hip_runtime.h>

#define N_NODES 32768
#define C_IN 128
#define C_W 32
#define KK 24
#define SS 5
#define GG 8      // nodes per k_node block (one per wave)
#define AGS (KK * C_W + 4)   // padded sAgg stride

// ---------------- colstats(x) for BN1 + edge histogram ----------------
__global__ void __launch_bounds__(256) k_pre(
        const float* __restrict__ x, float* __restrict__ s1,
        const int* __restrict__ ei, int E, int* __restrict__ counts) {
    int t = threadIdx.x;
    int c = t % C_IN;
    int r0 = blockIdx.x * 2 + t / C_IN;
    float s = 0.f, sq = 0.f;
    for (int r = r0; r < N_NODES; r += 1024) {
        float v = x[(size_t)r * C_IN + c];
        s += v; sq += v * v;
    }
    atomicAdd(&s1[c], s);
    atomicAdd(&s1[C_IN + c], sq);
    for (int e = blockIdx.x * 256 + t; e < E; e += 512 * 256)
        atomicAdd(&counts[ei[E + e]], 1);
}

// ---------------- input MLP: lrelu(bn1(x)) @ lin1_w (+ BN2 stats) ----------------
__global__ void __launch_bounds__(256) k_mlp1(
        const float* __restrict__ x, const float* __restrict__ s1,
        const float* __restrict__ g1, const float* __restrict__ b1,
        const float* __restrict__ w1, float* __restrict__ hpre,
        float* __restrict__ s2sh) {
    __shared__ float sAB[2][C_IN];
    __shared__ float sx[32][C_IN + 4];
    __shared__ float sw[C_IN][C_W];
    const int t = threadIdx.x;
    const int row0 = blockIdx.x * 32;
    if (t < C_IN) {
        float mean = s1[t] * (1.f / N_NODES);
        float var = s1[C_IN + t] * (1.f / N_NODES) - mean * mean;
        float a = g1[t] * rsqrtf(var + 1e-5f);
        sAB[0][t] = a; sAB[1][t] = b1[t] - mean * a;
    }
    for (int idx = t; idx < C_IN * C_W; idx += 256)
        sw[idx / C_W][idx % C_W] = w1[idx];
    __syncthreads();
    for (int idx = t; idx < 32 * 32; idx += 256) {
        int r = idx >> 5, cq = idx & 31;
        float4 v = *(const float4*)&x[(size_t)(row0 + r) * C_IN + cq * 4];
        float* d = &sx[r][cq * 4];
        float a0 = sAB[0][cq*4+0]*v.x + sAB[1][cq*4+0];
        float a1 = sAB[0][cq*4+1]*v.y + sAB[1][cq*4+1];
        float a2 = sAB[0][cq*4+2]*v.z + sAB[1][cq*4+2];
        float a3 = sAB[0][cq*4+3]*v.w + sAB[1][cq*4+3];
        d[0] = a0 >= 0.f ? a0 : 0.1f * a0;
        d[1] = a1 >= 0.f ? a1 : 0.1f * a1;
        d[2] = a2 >= 0.f ? a2 : 0.1f * a2;
        d[3] = a3 >= 0.f ? a3 : 0.1f * a3;
    }
    __syncthreads();
    const int r = t >> 3, c0 = (t & 7) * 4;
    float ac0 = 0.f, ac1 = 0.f, ac2 = 0.f, ac3 = 0.f;
    #pragma unroll 8
    for (int cc = 0; cc < C_IN; ++cc) {
        float xv = sx[r][cc];
        float4 wv = *(const float4*)&sw[cc][c0];
        ac0 += xv * wv.x; ac1 += xv * wv.y; ac2 += xv * wv.z; ac3 += xv * wv.w;
    }
    float4 o; o.x = ac0; o.y = ac1; o.z = ac2; o.w = ac3;
    *(float4*)&hpre[(size_t)(row0 + r) * C_W + c0] = o;
    __syncthreads();
    sx[r][c0] = ac0; sx[r][c0+1] = ac1; sx[r][c0+2] = ac2; sx[r][c0+3] = ac3;
    __syncthreads();
    if (t < C_W) {
        float s = 0.f, sq = 0.f;
        #pragma unroll
        for (int rr = 0; rr < 32; ++rr) {
            float v = sx[rr][t];
            s += v; sq += v * v;
        }
        int sh = (blockIdx.x & 7) * 64;
        atomicAdd(&s2sh[sh + t], s);
        atomicAdd(&s2sh[sh + C_W + t], sq);
    }
}

// ---------------- single-block scan (1024 thr x 32 elems, int4) ----------------
__global__ void __launch_bounds__(1024) k_scan(
        const int* __restrict__ counts, int* __restrict__ offsets,
        int* __restrict__ cursor) {
    __shared__ int sblk[1024];
    const int t = threadIdx.x;
    const int base = t * 32;
    const int4* cp = (const int4*)(counts + base);
    int loc[32];
    int s = 0;
    #pragma unroll
    for (int q = 0; q < 8; ++q) {
        int4 v = cp[q];
        loc[q*4+0] = s; s += v.x;
        loc[q*4+1] = s; s += v.y;
        loc[q*4+2] = s; s += v.z;
        loc[q*4+3] = s; s += v.w;
    }
    sblk[t] = s;
    __syncthreads();
    for (int d = 1; d < 1024; d <<= 1) {
        int u = (t >= d) ? sblk[t - d] : 0;
        __syncthreads();
        sblk[t] += u;
        __syncthreads();
    }
    const int blockbase = sblk[t] - s;
    #pragma unroll
    for (int q = 0; q < 8; ++q) {
        int4 o;
        o.x = blockbase + loc[q*4+0];
        o.y = blockbase + loc[q*4+1];
        o.z = blockbase + loc[q*4+2];
        o.w = blockbase + loc[q*4+3];
        ((int4*)(offsets + base))[q] = o;
        ((int4*)(cursor + base))[q] = o;
    }
    if (t == 1023) offsets[N_NODES] = sblk[1023];
}

// ---------------- edge kernel: WeightNet + scatter to CSR slots ----------------
__global__ void __launch_bounds__(256) k_edge(
        const int* __restrict__ ei, int E,
        const float* __restrict__ pos, const float* __restrict__ ori,
        const int* __restrict__ seq,
        const float* __restrict__ wnw, const float* __restrict__ wnb,
        int* __restrict__ cursor, int* __restrict__ srcPerm,
        float* __restrict__ wPerm) {
    __shared__ float sWnw[11][169];
    __shared__ float sWnb[11][24];
    const int t = threadIdx.x;
    for (int idx = t; idx < 11 * 168; idx += 256)
        sWnw[idx / 168][idx % 168] = wnw[idx];
    for (int idx = t; idx < 11 * 24; idx += 256)
        sWnb[idx / 24][idx % 24] = wnb[idx];
    __syncthreads();
    const int e = blockIdx.x * 256 + t;
    if (e >= E) return;
    const int src = ei[e];
    const int dst = ei[E + e];
    int ds = seq[src] - seq[dst];
    ds = ds < -SS ? -SS : (ds > SS ? SS : ds);
    const int sb = ds + SS;
    float dx = pos[src * 3 + 0] - pos[dst * 3 + 0];
    float dy = pos[src * 3 + 1] - pos[dst * 3 + 1];
    float dz = pos[src * 3 + 2] - pos[dst * 3 + 2];
    float dist = sqrtf(dx * dx + dy * dy + dz * dz);
    float inv = 1.f / (dist + 1e-9f);
    float ux = dx * inv, uy = dy * inv, uz = dz * inv;
    float b0 = ori[src * 9 + 0], b1 = ori[src * 9 + 1], b2 = ori[src * 9 + 2];
    float delta[7];
    #pragma unroll
    for (int r = 0; r < 3; ++r) {
        float m0 = ori[dst * 9 + r * 3 + 0];
        float m1 = ori[dst * 9 + r * 3 + 1];
        float m2 = ori[dst * 9 + r * 3 + 2];
        delta[r]     = m0 * ux + m1 * uy + m2 * uz;
        delta[3 + r] = m0 * b0 + m1 * b1 + m2 * b2;
    }
    delta[6] = dist * 0.125f;
    float w[KK];
    #pragma unroll
    for (int k = 0; k < KK; ++k) {
        float acc = sWnb[sb][k];
        #pragma unroll
        for (int f = 0; f < 7; ++f)
            acc += delta[f] * sWnw[sb][f * 24 + k];
        w[k] = acc >= 0.f ? acc : 0.2f * acc;
    }
    const int p = atomicAdd(&cursor[dst], 1);
    srcPerm[p] = src;
    float4* wp = (float4*)(wPerm + (size_t)p * KK);
    #pragma unroll
    for (int q = 0; q < 6; ++q) {
        float4 o; o.x = w[q*4]; o.y = w[q*4+1]; o.z = w[q*4+2]; o.w = w[q*4+3];
        wp[q] = o;
    }
}

// ---------------- aggregation + conv projection (+ BN3 stats) ----------------
// 512 threads = 8 waves; one node per wave (no divergence between CSR walks).
__global__ void __launch_bounds__(512, 4) k_node(
    const int* __restrict__ offsets, const int* __restrict__ srcPerm,
    const float* __restrict__ wPerm, const float* __restrict__ hpre,
    const float* __restrict__ s2sh, const float* __restrict__ g2,
    const float* __restrict__ b2, const float* __restrict__ convw,
    float* __restrict__ convout, float* __restrict__ s3sh) {
    __shared__ float sA2[C_W], sB2[C_W];
    __shared__ int sOff[GG + 1];
    __shared__ float sW[GG][32 * KK];      // staged per-wave weight batch
    __shared__ float sAgg[GG][AGS];
    __shared__ float sRed[8][GG][C_W];
    __shared__ float sRv[GG][C_W], sRq[GG][C_W];
    const int t = threadIdx.x;
    const int i0 = blockIdx.x * GG;
    if (t < C_W) {
        float s = 0.f, sq = 0.f;
        #pragma unroll
        for (int j = 0; j < 8; ++j) {
            s  += s2sh[j * 64 + t];
            sq += s2sh[j * 64 + C_W + t];
        }
        float mean = s * (1.f / N_NODES);
        float var = sq * (1.f / N_NODES) - mean * mean;
        float a = g2[t] * rsqrtf(var + 1e-5f);
        sA2[t] = a; sB2[t] = b2[t] - mean * a;
    }
    if (t <= GG) sOff[t] = offsets[i0 + t];
    __syncthreads();

    const int w    = t >> 6;      // wave id == node slot
    const int lane = t & 63;
    const int c    = lane & 31;   // channel
    const int s    = lane >> 5;   // edge parity within pair
    const float bnA = sA2[c], bnB = sB2[c];
    const int beg = sOff[w], end = sOff[w + 1];
    float* sWw = &sW[w][0];
    float a[KK];
    #pragma unroll
    for (int k = 0; k < KK; ++k) a[k] = 0.f;

    for (int cb = beg; cb < end; cb += 32) {
        const int m = min(32, end - cb);
        // preload 32 src indices (both halves hold copies by channel)
        int srcL = srcPerm[cb + min(c, m - 1)];
        // cooperative stage of m*24 floats into this wave's LDS slab
        const float4* gsrc = (const float4*)(wPerm + (size_t)cb * KK);
        #pragma unroll
        for (int u = 0; u < 3; ++u) {
            int idx = lane + u * 64;
            if (idx < m * 6) ((float4*)sWw)[idx] = gsrc[idx];
        }
        // wave-internal LDS ordering: no barrier needed
        #pragma unroll 2
        for (int j2 = 0; j2 < m; j2 += 2) {
            const int slot = min(j2 + s, m - 1);
            const bool ok = (j2 + s) < m;
            const int src = __shfl(srcL, slot, 64);
            float h = hpre[(size_t)src * C_W + c];
            float v = bnA * h + bnB;
            v = v >= 0.f ? v : 0.1f * v;
            v = ok ? v : 0.f;
            const float4* wp = (const float4*)(sWw + slot * KK);
            float4 W0 = wp[0], W1 = wp[1], W2 = wp[2];
            float4 W3 = wp[3], W4 = wp[4], W5 = wp[5];
            a[0]  += W0.x * v; a[1]  += W0.y * v; a[2]  += W0.z * v; a[3]  += W0.w * v;
            a[4]  += W1.x * v; a[5]  += W1.y * v; a[6]  += W1.z * v; a[7]  += W1.w * v;
            a[8]  += W2.x * v; a[9]  += W2.y * v; a[10] += W2.z * v; a[11] += W2.w * v;
            a[12] += W3.x * v; a[13] += W3.y * v; a[14] += W3.z * v; a[15] += W3.w * v;
            a[16] += W4.x * v; a[17] += W4.y * v; a[18] += W4.z * v; a[19] += W4.w * v;
            a[20] += W5.x * v; a[21] += W5.y * v; a[22] += W5.z * v; a[23] += W5.w * v;
        }
    }
    // fold the two halves
    #pragma unroll
    for (int k = 0; k < KK; ++k) a[k] += __shfl_xor(a[k], 32, 64);
    if (s == 0) {
        #pragma unroll
        for (int k = 0; k < KK; ++k) sAgg[w][k * C_W + c] = a[k];
    }
    __syncthreads();

    // projection: t = sl8*64 + gp*8 + coq ; each thread 96 rows x 4 cols
    {
        const int coq = t & 7;
        const int gp  = (t >> 3) & 7;
        const int sl8 = t >> 6;
        const int r0  = sl8 * 96;
        float4 acc; acc.x = acc.y = acc.z = acc.w = 0.f;
        #pragma unroll 6
        for (int rc = 0; rc < 96; rc += 4) {
            const float4 s4 = *(const float4*)&sAgg[gp][r0 + rc];
            const float4 w0 = *(const float4*)&convw[(size_t)(r0+rc+0)*32 + coq*4];
            const float4 w1 = *(const float4*)&convw[(size_t)(r0+rc+1)*32 + coq*4];
            const float4 w2 = *(const float4*)&convw[(size_t)(r0+rc+2)*32 + coq*4];
            const float4 w3 = *(const float4*)&convw[(size_t)(r0+rc+3)*32 + coq*4];
            acc.x += s4.x*w0.x + s4.y*w1.x + s4.z*w2.x + s4.w*w3.x;
            acc.y += s4.x*w0.y + s4.y*w1.y + s4.z*w2.y + s4.w*w3.y;
            acc.z += s4.x*w0.z + s4.y*w1.z + s4.z*w2.z + s4.w*w3.z;
            acc.w += s4.x*w0.w + s4.y*w1.w + s4.z*w2.w + s4.w*w3.w;
        }
        *(float4*)&sRed[sl8][gp][coq * 4] = acc;
    }
    __syncthreads();
    if (t < 256) {
        const int gg = t >> 5, co = t & 31;
        float v = 0.f;
        #pragma unroll
        for (int sl = 0; sl < 8; ++sl) v += sRed[sl][gg][co];
        convout[(size_t)(i0 + gg) * C_W + co] = v;
        sRv[gg][co] = v; sRq[gg][co] = v * v;
    }
    __syncthreads();
    if (t < 64) {
        int cc = t & 31;
        bool isq = t >= C_W;
        float s2 = 0.f;
        #pragma unroll
        for (int gg = 0; gg < GG; ++gg)
            s2 += isq ? sRq[gg][cc] : sRv[gg][cc];
        atomicAdd(&s3sh[(blockIdx.x & 7) * 64 + t], s2);
    }
}

// ---------------- output: lrelu(bn3(conv)) @ lin2_w + x (float4) ----------------
__global__ void __launch_bounds__(256) k_out(
        const float* __restrict__ conv, const float* __restrict__ s3sh,
        const float* __restrict__ g3, const float* __restrict__ b3,
        const float* __restrict__ w2, const float* __restrict__ x,
        float* __restrict__ out) {
    __shared__ float sAB[2][C_W];
    __shared__ float sh[8][C_W];
    __shared__ float sw2[C_W][C_IN];
    const int t = threadIdx.x;
    const int row0 = blockIdx.x * 8;
    if (t < C_W) {
        float s = 0.f, sq = 0.f;
        #pragma unroll
        for (int j = 0; j < 8; ++j) {
            s  += s3sh[j * 64 + t];
            sq += s3sh[j * 64 + C_W + t];
        }
        float mean = s * (1.f / N_NODES);
        float var = sq * (1.f / N_NODES) - mean * mean;
        float a = g3[t] * rsqrtf(var + 1e-5f);
        sAB[0][t] = a; sAB[1][t] = b3[t] - mean * a;
    }
    for (int idx = t; idx < C_W * C_IN; idx += 256)
        sw2[idx >> 7][idx & 127] = w2[idx];
    __syncthreads();
    {
        float v = conv[(size_t)row0 * C_W + t];
        int r = t >> 5, cc = t & 31;
        v = sAB[0][cc] * v + sAB[1][cc];
        sh[r][cc] = v >= 0.f ? v : 0.1f * v;
    }
    __syncthreads();
    const int r = t >> 5, c4 = (t & 31) * 4;
    float4 acc = *(const float4*)&x[(size_t)(row0 + r) * C_IN + c4];
    #pragma unroll 8
    for (int cw = 0; cw < C_W; ++cw) {
        float hv = sh[r][cw];
        float4 wv = *(const float4*)&sw2[cw][c4];
        acc.x += hv * wv.x; acc.y += hv * wv.y;
        acc.z += hv * wv.z; acc.w += hv * wv.w;
    }
    *(float4*)&out[(size_t)(row0 + r) * C_IN + c4] = acc;
}

extern "C" void kernel_launch(void* const* d_in, const int* in_sizes, int n_in,
                              void* d_out, int out_size, void* d_ws, size_t ws_size,
                              hipStream_t stream) {
    const float* x     = (const float*)d_in[0];
    const float* pos   = (const float*)d_in[1];
    const float* ori   = (const float*)d_in[2];
    const int*   seq   = (const int*)d_in[3];
    const int*   ei    = (const int*)d_in[4];
    const float* bn1g  = (const float*)d_in[5];
    const float* bn1b  = (const float*)d_in[6];
    const float* lin1w = (const float*)d_in[7];
    const float* bn2g  = (const float*)d_in[8];
    const float* bn2b  = (const float*)d_in[9];
    const float* wnw   = (const float*)d_in[10];
    const float* wnb   = (const float*)d_in[11];
    const float* convw = (const float*)d_in[12];
    const float* bn3g  = (const float*)d_in[13];
    const float* bn3b  = (const float*)d_in[14];
    const float* lin2w = (const float*)d_in[15];
    float* out = (float*)d_out;
    const int E = in_sizes[4] / 2;

    char* wsb = (char*)d_ws;
    size_t off = 0;
    auto alloc = [&](size_t bytes) {
        void* p = wsb + off;
        off = (off + bytes + 255) & ~(size_t)255;
        return p;
    };
    float* s1      = (float*)alloc(256 * 4);
    float* s2sh    = (float*)alloc(512 * 4);
    float* s3sh    = (float*)alloc(512 * 4);
    int*   counts  = (int*)alloc((size_t)N_NODES * 4);
    size_t zero_bytes = off;
    int*   offsets = (int*)alloc(((size_t)N_NODES + 1) * 4);
    int*   cursor  = (int*)alloc((size_t)N_NODES * 4);
    int*   srcPerm = (int*)alloc((size_t)E * 4);
    float* hpre    = (float*)alloc((size_t)N_NODES * C_W * 4);
    float* convo   = (float*)alloc((size_t)N_NODES * C_W * 4);
    float* wPerm   = (float*)alloc((size_t)E * KK * 4);

    hipMemsetAsync(wsb, 0, zero_bytes, stream);

    k_pre<<<512, 256, 0, stream>>>(x, s1, ei, E, counts);
    k_scan<<<1, 1024, 0, stream>>>(counts, offsets, cursor);
    k_edge<<<(E + 255) / 256, 256, 0, stream>>>(ei, E, pos, ori, seq, wnw, wnb,
                                                cursor, srcPerm, wPerm);
    k_mlp1<<<N_NODES / 32, 256, 0, stream>>>(x, s1, bn1g, bn1b, lin1w, hpre, s2sh);
    k_node<<<N_NODES / GG, 512, 0, stream>>>(offsets, srcPerm, wPerm, hpre,
                                             s2sh, bn2g, bn2b, convw, convo, s3sh);
    k_out<<<N_NODES / 8, 256, 0, stream>>>(convo, s3sh, bn3g, bn3b, lin2w, x, out);
}

// Round 8
// 261.224 us; speedup vs baseline: 1.1221x; 1.0536x over previous
//
#include <hip/hip_runtime.h>

#define N_NODES 32768
#define C_IN 128
#define C_W 32
#define KK 24
#define SS 5
#define GG 8      // nodes per k_node block (one per wave)
#define AGS (KK * C_W + 4)   // padded sAgg stride

// ---------------- colstats(x) for BN1 + edge histogram ----------------
__global__ void __launch_bounds__(256) k_pre(
        const float* __restrict__ x, float* __restrict__ s1,
        const int* __restrict__ ei, int E, int* __restrict__ counts) {
    int t = threadIdx.x;
    int c = t % C_IN;
    int r0 = blockIdx.x * 2 + t / C_IN;
    float s = 0.f, sq = 0.f;
    for (int r = r0; r < N_NODES; r += 1024) {
        float v = x[(size_t)r * C_IN + c];
        s += v; sq += v * v;
    }
    atomicAdd(&s1[c], s);
    atomicAdd(&s1[C_IN + c], sq);
    for (int e = blockIdx.x * 256 + t; e < E; e += 512 * 256)
        atomicAdd(&counts[ei[E + e]], 1);
}

// ---------------- input MLP: lrelu(bn1(x)) @ lin1_w (+ BN2 stats) ----------------
__global__ void __launch_bounds__(256) k_mlp1(
        const float* __restrict__ x, const float* __restrict__ s1,
        const float* __restrict__ g1, const float* __restrict__ b1,
        const float* __restrict__ w1, float* __restrict__ hpre,
        float* __restrict__ s2sh) {
    __shared__ float sAB[2][C_IN];
    __shared__ float sx[32][C_IN + 4];
    __shared__ float sw[C_IN][C_W];
    const int t = threadIdx.x;
    const int row0 = blockIdx.x * 32;
    if (t < C_IN) {
        float mean = s1[t] * (1.f / N_NODES);
        float var = s1[C_IN + t] * (1.f / N_NODES) - mean * mean;
        float a = g1[t] * rsqrtf(var + 1e-5f);
        sAB[0][t] = a; sAB[1][t] = b1[t] - mean * a;
    }
    for (int idx = t; idx < C_IN * C_W; idx += 256)
        sw[idx / C_W][idx % C_W] = w1[idx];
    __syncthreads();
    for (int idx = t; idx < 32 * 32; idx += 256) {
        int r = idx >> 5, cq = idx & 31;
        float4 v = *(const float4*)&x[(size_t)(row0 + r) * C_IN + cq * 4];
        float* d = &sx[r][cq * 4];
        float a0 = sAB[0][cq*4+0]*v.x + sAB[1][cq*4+0];
        float a1 = sAB[0][cq*4+1]*v.y + sAB[1][cq*4+1];
        float a2 = sAB[0][cq*4+2]*v.z + sAB[1][cq*4+2];
        float a3 = sAB[0][cq*4+3]*v.w + sAB[1][cq*4+3];
        d[0] = a0 >= 0.f ? a0 : 0.1f * a0;
        d[1] = a1 >= 0.f ? a1 : 0.1f * a1;
        d[2] = a2 >= 0.f ? a2 : 0.1f * a2;
        d[3] = a3 >= 0.f ? a3 : 0.1f * a3;
    }
    __syncthreads();
    const int r = t >> 3, c0 = (t & 7) * 4;
    float ac0 = 0.f, ac1 = 0.f, ac2 = 0.f, ac3 = 0.f;
    #pragma unroll 8
    for (int cc = 0; cc < C_IN; ++cc) {
        float xv = sx[r][cc];
        float4 wv = *(const float4*)&sw[cc][c0];
        ac0 += xv * wv.x; ac1 += xv * wv.y; ac2 += xv * wv.z; ac3 += xv * wv.w;
    }
    float4 o; o.x = ac0; o.y = ac1; o.z = ac2; o.w = ac3;
    *(float4*)&hpre[(size_t)(row0 + r) * C_W + c0] = o;
    __syncthreads();
    sx[r][c0] = ac0; sx[r][c0+1] = ac1; sx[r][c0+2] = ac2; sx[r][c0+3] = ac3;
    __syncthreads();
    if (t < C_W) {
        float s = 0.f, sq = 0.f;
        #pragma unroll
        for (int rr = 0; rr < 32; ++rr) {
            float v = sx[rr][t];
            s += v; sq += v * v;
        }
        int sh = (blockIdx.x & 7) * 64;
        atomicAdd(&s2sh[sh + t], s);
        atomicAdd(&s2sh[sh + C_W + t], sq);
    }
}

// ---------------- single-block scan (1024 thr x 32 elems, int4) ----------------
__global__ void __launch_bounds__(1024) k_scan(
        const int* __restrict__ counts, int* __restrict__ offsets,
        int* __restrict__ cursor) {
    __shared__ int sblk[1024];
    const int t = threadIdx.x;
    const int base = t * 32;
    const int4* cp = (const int4*)(counts + base);
    int loc[32];
    int s = 0;
    #pragma unroll
    for (int q = 0; q < 8; ++q) {
        int4 v = cp[q];
        loc[q*4+0] = s; s += v.x;
        loc[q*4+1] = s; s += v.y;
        loc[q*4+2] = s; s += v.z;
        loc[q*4+3] = s; s += v.w;
    }
    sblk[t] = s;
    __syncthreads();
    for (int d = 1; d < 1024; d <<= 1) {
        int u = (t >= d) ? sblk[t - d] : 0;
        __syncthreads();
        sblk[t] += u;
        __syncthreads();
    }
    const int blockbase = sblk[t] - s;
    #pragma unroll
    for (int q = 0; q < 8; ++q) {
        int4 o;
        o.x = blockbase + loc[q*4+0];
        o.y = blockbase + loc[q*4+1];
        o.z = blockbase + loc[q*4+2];
        o.w = blockbase + loc[q*4+3];
        ((int4*)(offsets + base))[q] = o;
        ((int4*)(cursor + base))[q] = o;
    }
    if (t == 1023) offsets[N_NODES] = sblk[1023];
}

// ---------------- edge kernel: WeightNet + scatter to CSR slots ----------------
__global__ void __launch_bounds__(256) k_edge(
        const int* __restrict__ ei, int E,
        const float* __restrict__ pos, const float* __restrict__ ori,
        const int* __restrict__ seq,
        const float* __restrict__ wnw, const float* __restrict__ wnb,
        int* __restrict__ cursor, int* __restrict__ srcPerm,
        float* __restrict__ wPerm) {
    __shared__ float sWnw[11][169];
    __shared__ float sWnb[11][24];
    const int t = threadIdx.x;
    for (int idx = t; idx < 11 * 168; idx += 256)
        sWnw[idx / 168][idx % 168] = wnw[idx];
    for (int idx = t; idx < 11 * 24; idx += 256)
        sWnb[idx / 24][idx % 24] = wnb[idx];
    __syncthreads();
    const int e = blockIdx.x * 256 + t;
    if (e >= E) return;
    const int src = ei[e];
    const int dst = ei[E + e];
    int ds = seq[src] - seq[dst];
    ds = ds < -SS ? -SS : (ds > SS ? SS : ds);
    const int sb = ds + SS;
    float dx = pos[src * 3 + 0] - pos[dst * 3 + 0];
    float dy = pos[src * 3 + 1] - pos[dst * 3 + 1];
    float dz = pos[src * 3 + 2] - pos[dst * 3 + 2];
    float dist = sqrtf(dx * dx + dy * dy + dz * dz);
    float inv = 1.f / (dist + 1e-9f);
    float ux = dx * inv, uy = dy * inv, uz = dz * inv;
    float b0 = ori[src * 9 + 0], b1 = ori[src * 9 + 1], b2 = ori[src * 9 + 2];
    float delta[7];
    #pragma unroll
    for (int r = 0; r < 3; ++r) {
        float m0 = ori[dst * 9 + r * 3 + 0];
        float m1 = ori[dst * 9 + r * 3 + 1];
        float m2 = ori[dst * 9 + r * 3 + 2];
        delta[r]     = m0 * ux + m1 * uy + m2 * uz;
        delta[3 + r] = m0 * b0 + m1 * b1 + m2 * b2;
    }
    delta[6] = dist * 0.125f;
    float w[KK];
    #pragma unroll
    for (int k = 0; k < KK; ++k) {
        float acc = sWnb[sb][k];
        #pragma unroll
        for (int f = 0; f < 7; ++f)
            acc += delta[f] * sWnw[sb][f * 24 + k];
        w[k] = acc >= 0.f ? acc : 0.2f * acc;
    }
    const int p = atomicAdd(&cursor[dst], 1);
    srcPerm[p] = src;
    float4* wp = (float4*)(wPerm + (size_t)p * KK);
    #pragma unroll
    for (int q = 0; q < 6; ++q) {
        float4 o; o.x = w[q*4]; o.y = w[q*4+1]; o.z = w[q*4+2]; o.w = w[q*4+3];
        wp[q] = o;
    }
}

// ---------------- aggregation + conv projection (+ BN3 stats) ----------------
// 512 threads = 8 waves; one node per wave. Fixed 8-edge chunks with
// explicitly hoisted gathers (4 independent loads in flight before FMAs).
__global__ void __launch_bounds__(512, 4) k_node(
    const int* __restrict__ offsets, const int* __restrict__ srcPerm,
    const float* __restrict__ wPerm, const float* __restrict__ hpre,
    const float* __restrict__ s2sh, const float* __restrict__ g2,
    const float* __restrict__ b2, const float* __restrict__ convw,
    float* __restrict__ convout, float* __restrict__ s3sh) {
    __shared__ float sA2[C_W], sB2[C_W];
    __shared__ int sOff[GG + 1];
    __shared__ float sW[GG][32 * KK];
    __shared__ float sAgg[GG][AGS];
    __shared__ float sRed[8][GG][C_W];
    __shared__ float sRv[GG][C_W], sRq[GG][C_W];
    const int t = threadIdx.x;
    const int i0 = blockIdx.x * GG;
    if (t < C_W) {
        float s = 0.f, sq = 0.f;
        #pragma unroll
        for (int j = 0; j < 8; ++j) {
            s  += s2sh[j * 64 + t];
            sq += s2sh[j * 64 + C_W + t];
        }
        float mean = s * (1.f / N_NODES);
        float var = sq * (1.f / N_NODES) - mean * mean;
        float a = g2[t] * rsqrtf(var + 1e-5f);
        sA2[t] = a; sB2[t] = b2[t] - mean * a;
    }
    if (t <= GG) sOff[t] = offsets[i0 + t];
    __syncthreads();

    const int w    = t >> 6;
    const int lane = t & 63;
    const int c    = lane & 31;
    const int s    = lane >> 5;
    const float bnA = sA2[c], bnB = sB2[c];
    const int beg = sOff[w], end = sOff[w + 1];
    float* sWw = &sW[w][0];
    float a[KK];
    #pragma unroll
    for (int k = 0; k < KK; ++k) a[k] = 0.f;

    for (int cb = beg; cb < end; cb += 32) {
        const int m = min(32, end - cb);
        int srcL = srcPerm[cb + min(c, m - 1)];
        const float4* gsrc = (const float4*)(wPerm + (size_t)cb * KK);
        #pragma unroll
        for (int u = 0; u < 3; ++u) {
            int idx = lane + u * 64;
            if (idx < m * 6) ((float4*)sWw)[idx] = gsrc[idx];
        }
        const int m8 = m & ~7;
        for (int j8 = 0; j8 < m8; j8 += 8) {
            // hoisted: 4 independent gathers before any FMA
            const int q0 = __shfl(srcL, j8 + 0 + s, 64);
            const int q1 = __shfl(srcL, j8 + 2 + s, 64);
            const int q2 = __shfl(srcL, j8 + 4 + s, 64);
            const int q3 = __shfl(srcL, j8 + 6 + s, 64);
            float h0 = hpre[(size_t)q0 * C_W + c];
            float h1 = hpre[(size_t)q1 * C_W + c];
            float h2 = hpre[(size_t)q2 * C_W + c];
            float h3 = hpre[(size_t)q3 * C_W + c];
            #pragma unroll
            for (int q = 0; q < 4; ++q) {
                float h = q == 0 ? h0 : (q == 1 ? h1 : (q == 2 ? h2 : h3));
                float v = bnA * h + bnB;
                v = v >= 0.f ? v : 0.1f * v;
                const float4* wp = (const float4*)(sWw + (j8 + 2 * q + s) * KK);
                float4 W0 = wp[0], W1 = wp[1], W2 = wp[2];
                float4 W3 = wp[3], W4 = wp[4], W5 = wp[5];
                a[0]  += W0.x * v; a[1]  += W0.y * v; a[2]  += W0.z * v; a[3]  += W0.w * v;
                a[4]  += W1.x * v; a[5]  += W1.y * v; a[6]  += W1.z * v; a[7]  += W1.w * v;
                a[8]  += W2.x * v; a[9]  += W2.y * v; a[10] += W2.z * v; a[11] += W2.w * v;
                a[12] += W3.x * v; a[13] += W3.y * v; a[14] += W3.z * v; a[15] += W3.w * v;
                a[16] += W4.x * v; a[17] += W4.y * v; a[18] += W4.z * v; a[19] += W4.w * v;
                a[20] += W5.x * v; a[21] += W5.y * v; a[22] += W5.z * v; a[23] += W5.w * v;
            }
        }
        // tail: < 8 edges, masked 2-per-iter
        for (int j2 = m8; j2 < m; j2 += 2) {
            const int slot = min(j2 + s, m - 1);
            const bool ok = (j2 + s) < m;
            const int src = __shfl(srcL, slot, 64);
            float h = hpre[(size_t)src * C_W + c];
            float v = bnA * h + bnB;
            v = v >= 0.f ? v : 0.1f * v;
            v = ok ? v : 0.f;
            const float4* wp = (const float4*)(sWw + slot * KK);
            float4 W0 = wp[0], W1 = wp[1], W2 = wp[2];
            float4 W3 = wp[3], W4 = wp[4], W5 = wp[5];
            a[0]  += W0.x * v; a[1]  += W0.y * v; a[2]  += W0.z * v; a[3]  += W0.w * v;
            a[4]  += W1.x * v; a[5]  += W1.y * v; a[6]  += W1.z * v; a[7]  += W1.w * v;
            a[8]  += W2.x * v; a[9]  += W2.y * v; a[10] += W2.z * v; a[11] += W2.w * v;
            a[12] += W3.x * v; a[13] += W3.y * v; a[14] += W3.z * v; a[15] += W3.w * v;
            a[16] += W4.x * v; a[17] += W4.y * v; a[18] += W4.z * v; a[19] += W4.w * v;
            a[20] += W5.x * v; a[21] += W5.y * v; a[22] += W5.z * v; a[23] += W5.w * v;
        }
    }
    #pragma unroll
    for (int k = 0; k < KK; ++k) a[k] += __shfl_xor(a[k], 32, 64);
    if (s == 0) {
        #pragma unroll
        for (int k = 0; k < KK; ++k) sAgg[w][k * C_W + c] = a[k];
    }
    __syncthreads();

    {
        const int coq = t & 7;
        const int gp  = (t >> 3) & 7;
        const int sl8 = t >> 6;
        const int r0  = sl8 * 96;
        float4 acc; acc.x = acc.y = acc.z = acc.w = 0.f;
        #pragma unroll 6
        for (int rc = 0; rc < 96; rc += 4) {
            const float4 s4 = *(const float4*)&sAgg[gp][r0 + rc];
            const float4 w0 = *(const float4*)&convw[(size_t)(r0+rc+0)*32 + coq*4];
            const float4 w1 = *(const float4*)&convw[(size_t)(r0+rc+1)*32 + coq*4];
            const float4 w2 = *(const float4*)&convw[(size_t)(r0+rc+2)*32 + coq*4];
            const float4 w3 = *(const float4*)&convw[(size_t)(r0+rc+3)*32 + coq*4];
            acc.x += s4.x*w0.x + s4.y*w1.x + s4.z*w2.x + s4.w*w3.x;
            acc.y += s4.x*w0.y + s4.y*w1.y + s4.z*w2.y + s4.w*w3.y;
            acc.z += s4.x*w0.z + s4.y*w1.z + s4.z*w2.z + s4.w*w3.z;
            acc.w += s4.x*w0.w + s4.y*w1.w + s4.z*w2.w + s4.w*w3.w;
        }
        *(float4*)&sRed[sl8][gp][coq * 4] = acc;
    }
    __syncthreads();
    if (t < 256) {
        const int gg = t >> 5, co = t & 31;
        float v = 0.f;
        #pragma unroll
        for (int sl = 0; sl < 8; ++sl) v += sRed[sl][gg][co];
        convout[(size_t)(i0 + gg) * C_W + co] = v;
        sRv[gg][co] = v; sRq[gg][co] = v * v;
    }
    __syncthreads();
    if (t < 64) {
        int cc = t & 31;
        bool isq = t >= C_W;
        float s2 = 0.f;
        #pragma unroll
        for (int gg = 0; gg < GG; ++gg)
            s2 += isq ? sRq[gg][cc] : sRv[gg][cc];
        atomicAdd(&s3sh[(blockIdx.x & 7) * 64 + t], s2);
    }
}

// ---------------- output: lrelu(bn3(conv)) @ lin2_w + x (float4) ----------------
__global__ void __launch_bounds__(256) k_out(
        const float* __restrict__ conv, const float* __restrict__ s3sh,
        const float* __restrict__ g3, const float* __restrict__ b3,
        const float* __restrict__ w2, const float* __restrict__ x,
        float* __restrict__ out) {
    __shared__ float sAB[2][C_W];
    __shared__ float sh[8][C_W];
    __shared__ float sw2[C_W][C_IN];
    const int t = threadIdx.x;
    const int row0 = blockIdx.x * 8;
    if (t < C_W) {
        float s = 0.f, sq = 0.f;
        #pragma unroll
        for (int j = 0; j < 8; ++j) {
            s  += s3sh[j * 64 + t];
            sq += s3sh[j * 64 + C_W + t];
        }
        float mean = s * (1.f / N_NODES);
        float var = sq * (1.f / N_NODES) - mean * mean;
        float a = g3[t] * rsqrtf(var + 1e-5f);
        sAB[0][t] = a; sAB[1][t] = b3[t] - mean * a;
    }
    for (int idx = t; idx < C_W * C_IN; idx += 256)
        sw2[idx >> 7][idx & 127] = w2[idx];
    __syncthreads();
    {
        float v = conv[(size_t)row0 * C_W + t];
        int r = t >> 5, cc = t & 31;
        v = sAB[0][cc] * v + sAB[1][cc];
        sh[r][cc] = v >= 0.f ? v : 0.1f * v;
    }
    __syncthreads();
    const int r = t >> 5, c4 = (t & 31) * 4;
    float4 acc = *(const float4*)&x[(size_t)(row0 + r) * C_IN + c4];
    #pragma unroll 8
    for (int cw = 0; cw < C_W; ++cw) {
        float hv = sh[r][cw];
        float4 wv = *(const float4*)&sw2[cw][c4];
        acc.x += hv * wv.x; acc.y += hv * wv.y;
        acc.z += hv * wv.z; acc.w += hv * wv.w;
    }
    *(float4*)&out[(size_t)(row0 + r) * C_IN + c4] = acc;
}

extern "C" void kernel_launch(void* const* d_in, const int* in_sizes, int n_in,
                              void* d_out, int out_size, void* d_ws, size_t ws_size,
                              hipStream_t stream) {
    const float* x     = (const float*)d_in[0];
    const float* pos   = (const float*)d_in[1];
    const float* ori   = (const float*)d_in[2];
    const int*   seq   = (const int*)d_in[3];
    const int*   ei    = (const int*)d_in[4];
    const float* bn1g  = (const float*)d_in[5];
    const float* bn1b  = (const float*)d_in[6];
    const float* lin1w = (const float*)d_in[7];
    const float* bn2g  = (const float*)d_in[8];
    const float* bn2b  = (const float*)d_in[9];
    const float* wnw   = (const float*)d_in[10];
    const float* wnb   = (const float*)d_in[11];
    const float* convw = (const float*)d_in[12];
    const float* bn3g  = (const float*)d_in[13];
    const float* bn3b  = (const float*)d_in[14];
    const float* lin2w = (const float*)d_in[15];
    float* out = (float*)d_out;
    const int E = in_sizes[4] / 2;

    char* wsb = (char*)d_ws;
    size_t off = 0;
    auto alloc = [&](size_t bytes) {
        void* p = wsb + off;
        off = (off + bytes + 255) & ~(size_t)255;
        return p;
    };
    float* s1      = (float*)alloc(256 * 4);
    float* s2sh    = (float*)alloc(512 * 4);
    float* s3sh    = (float*)alloc(512 * 4);
    int*   counts  = (int*)alloc((size_t)N_NODES * 4);
    size_t zero_bytes = off;
    int*   offsets = (int*)alloc(((size_t)N_NODES + 1) * 4);
    int*   cursor  = (int*)alloc((size_t)N_NODES * 4);
    int*   srcPerm = (int*)alloc((size_t)E * 4);
    float* hpre    = (float*)alloc((size_t)N_NODES * C_W * 4);
    float* convo   = (float*)alloc((size_t)N_NODES * C_W * 4);
    float* wPerm   = (float*)alloc((size_t)E * KK * 4);

    hipMemsetAsync(wsb, 0, zero_bytes, stream);

    k_pre<<<512, 256, 0, stream>>>(x, s1, ei, E, counts);
    k_scan<<<1, 1024, 0, stream>>>(counts, offsets, cursor);
    k_edge<<<(E + 255) / 256, 256, 0, stream>>>(ei, E, pos, ori, seq, wnw, wnb,
                                                cursor, srcPerm, wPerm);
    k_mlp1<<<N_NODES / 32, 256, 0, stream>>>(x, s1, bn1g, bn1b, lin1w, hpre, s2sh);
    k_node<<<N_NODES / GG, 512, 0, stream>>>(offsets, srcPerm, wPerm, hpre,
                                             s2sh, bn2g, bn2b, convw, convo, s3sh);
    k_out<<<N_NODES / 8, 256, 0, stream>>>(convo, s3sh, bn3g, bn3b, lin2w, x, out);
}